// Round 4
// baseline (505.643 us; speedup 1.0000x reference)
//
#include <hip/hip_runtime.h>
#include <hip/hip_cooperative_groups.h>

namespace cg = cooperative_groups;

#define IMG    224
#define NPIX   (IMG * IMG)       // 50176
#define NELEM  (NPIX * 3)        // 150528
#define KSEL   12544             // 0.25 * IMG * IMG
#define NBINS  4096
#define MAXCAND 1024
#define BLOCK  1024
#define NWAVE  (BLOCK / 64)      // 16
#define SPLIT  2                 // blocks per sample
#define NPIX4  (NPIX / 4)        // 12544 pixel-float4 groups per sample
#define GVEC   (NELEM / 4)       // 37632 grad float4 per sample
#define HGVEC  (GVEC / SPLIT)    // 18816 grad float4 per half
#define PGRP   (NPIX4 / SPLIT)   // 6272 pixel groups per half
#define NMWH   (NPIX / SPLIT / 32) // 784 mask words per half
#define EVH    (3 * PGRP)        // 18816 data/out float4 per half

typedef float f4 __attribute__((ext_vector_type(4)));

__device__ __forceinline__ int binof(float x) {
    return min((int)(x * 4096.0f), NBINS - 1);
}

// spread 8 bits of b to positions 0,4,8,...,28
__device__ __forceinline__ unsigned int spread4(unsigned int x) {
    x = (x | (x << 12)) & 0x000F000Fu;
    x = (x | (x << 6))  & 0x03030303u;
    x = (x | (x << 3))  & 0x11111111u;
    return x;
}

// ---- shared device pieces ----

// 4096-bin histogram of one half of one sample's grad into LDS hist lh
__device__ __forceinline__ void hist_accum(const f4* __restrict__ g4h,
                                           unsigned int* lh, int tid)
{
    int i = tid;
    for (; i + 3 * BLOCK < HGVEC; i += 4 * BLOCK) {
        f4 v0 = g4h[i];
        f4 v1 = g4h[i + BLOCK];
        f4 v2 = g4h[i + 2 * BLOCK];
        f4 v3 = g4h[i + 3 * BLOCK];
        #pragma unroll
        for (int c = 0; c < 4; ++c) atomicAdd(&lh[binof(v0[c])], 1u);
        #pragma unroll
        for (int c = 0; c < 4; ++c) atomicAdd(&lh[binof(v1[c])], 1u);
        #pragma unroll
        for (int c = 0; c < 4; ++c) atomicAdd(&lh[binof(v2[c])], 1u);
        #pragma unroll
        for (int c = 0; c < 4; ++c) atomicAdd(&lh[binof(v3[c])], 1u);
    }
    for (; i < HGVEC; i += BLOCK) {
        f4 v = g4h[i];
        #pragma unroll
        for (int c = 0; c < 4; ++c) atomicAdd(&lh[binof(v[c])], 1u);
    }
}

// suffix-scan over 1024 groups of 4 bins; writes sB1/sR (LDS) and barriers
__device__ __forceinline__ void threshold_scan(
    unsigned int h0, unsigned int h1, unsigned int h2, unsigned int h3,
    unsigned int* wtot, int* sB1, unsigned int* sR, int tid)
{
    const int lane = tid & 63;
    const int wid  = tid >> 6;
    unsigned int s = h0 + h1 + h2 + h3;
    unsigned int v = s;
    #pragma unroll
    for (int off = 1; off < 64; off <<= 1) {
        unsigned int u = __shfl_down(v, off);
        if (lane + off < 64) v += u;
    }
    if (lane == 0) wtot[wid] = v;
    __syncthreads();
    unsigned int woff = 0;
    for (int w = wid + 1; w < NWAVE; ++w) woff += wtot[w];
    unsigned int a  = v + woff;   // suffix sum starting at group tid
    unsigned int nx = a - s;      // suffix sum starting at group tid+1
    if (a >= KSEL && nx < KSEL) {
        unsigned int hh[4] = {h0, h1, h2, h3};
        unsigned int cum = nx;
        for (int i = 3; i >= 0; --i) {
            cum += hh[i];
            if (cum >= KSEL) {
                *sB1 = 4 * tid + i;
                *sR  = KSEL - (cum - hh[i]);
                break;
            }
        }
    }
    __syncthreads();
}

// phase A (ballot mask build + candidate compaction) + phase B (coalesced copy)
__device__ __forceinline__ void classify_copy(
    const f4* __restrict__ g4, const f4* __restrict__ d4, f4* __restrict__ o4,
    int half, int B1, unsigned int* maskw,
    unsigned int* cnt, unsigned int* ck, unsigned int* ci, int tid)
{
    const int lane = tid & 63;
    const int wid  = tid >> 6;

    auto push = [&](float val, unsigned int idx) {
        unsigned int c2 = atomicAdd(cnt, 1u);
        if (c2 < MAXCAND) {
            ck[c2] = __float_as_uint(val);   // nonneg: uint order == float order
            ci[c2] = idx;
        }
    };

    // ---- phase A: grad planes (coalesced) -> mask words via ballot ----
    for (int q0 = 0; q0 < PGRP; q0 += BLOCK) {
        const int q   = q0 + tid;
        const bool inb = q < PGRP;
        const int G   = half * PGRP + q;
        f4 pa = {0.f, 0.f, 0.f, 0.f}, pb = pa, pc = pa;
        if (inb) {
            pa = g4[G];
            pb = g4[G + NPIX4];
            pc = g4[G + 2 * NPIX4];
        }
        bool m[4];
        #pragma unroll
        for (int j = 0; j < 4; ++j) {
            int ba = binof(pa[j]);
            int bb = binof(pb[j]);
            int bc = binof(pc[j]);
            m[j] = inb && ((ba > B1) || (bb > B1) || (bc > B1));
            unsigned int p = (unsigned int)(4 * G + j);
            if (inb && ba == B1) push(pa[j], p);
            if (inb && bb == B1) push(pb[j], p + NPIX);
            if (inb && bc == B1) push(pc[j], p + 2 * NPIX);
        }
        unsigned long long bl[4];
        #pragma unroll
        for (int j = 0; j < 4; ++j) bl[j] = __ballot(m[j]);

        const int qb = q0 + wid * 64;          // wave's q base
        if (lane < 8 && qb < PGRP) {
            unsigned int w =
                  spread4((unsigned int)(bl[0] >> (8 * lane)) & 0xFFu)
                | (spread4((unsigned int)(bl[1] >> (8 * lane)) & 0xFFu) << 1)
                | (spread4((unsigned int)(bl[2] >> (8 * lane)) & 0xFFu) << 2)
                | (spread4((unsigned int)(bl[3] >> (8 * lane)) & 0xFFu) << 3);
            maskw[(qb >> 3) + lane] = w;       // local pixel word
        }
    }
    __syncthreads();

    // ---- phase B: fully coalesced masked copy (lane-contiguous float4) ----
    const f4* dh = d4 + (size_t)half * EVH;
    f4*       oh = o4 + (size_t)half * EVH;
    auto msk = [&](int lp) -> unsigned int {
        return (maskw[lp >> 5] >> (lp & 31)) & 1u;
    };
    auto app = [&](f4 v, int i) -> f4 {
        int x = 4 * i;                          // local element index
        int p0 = x / 3, p1 = (x + 1) / 3, p2 = (x + 2) / 3, p3 = (x + 3) / 3;
        if (msk(p0)) v.x = 0.0f;
        if (msk(p1)) v.y = 0.0f;
        if (msk(p2)) v.z = 0.0f;
        if (msk(p3)) v.w = 0.0f;
        return v;
    };
    int i = tid;
    for (; i + 3 * BLOCK < EVH; i += 4 * BLOCK) {
        f4 v0 = __builtin_nontemporal_load(&dh[i]);
        f4 v1 = __builtin_nontemporal_load(&dh[i + BLOCK]);
        f4 v2 = __builtin_nontemporal_load(&dh[i + 2 * BLOCK]);
        f4 v3 = __builtin_nontemporal_load(&dh[i + 3 * BLOCK]);
        __builtin_nontemporal_store(app(v0, i),             &oh[i]);
        __builtin_nontemporal_store(app(v1, i + BLOCK),     &oh[i + BLOCK]);
        __builtin_nontemporal_store(app(v2, i + 2 * BLOCK), &oh[i + 2 * BLOCK]);
        __builtin_nontemporal_store(app(v3, i + 3 * BLOCK), &oh[i + 3 * BLOCK]);
    }
    for (; i < EVH; i += BLOCK) {
        f4 v = __builtin_nontemporal_load(&dh[i]);
        __builtin_nontemporal_store(app(v, i), &oh[i]);
    }
}

// exact rank among bin==B1 candidates; zero selected pixels
__device__ __forceinline__ void rank_fix(
    float* __restrict__ o, const unsigned int* __restrict__ ck,
    const unsigned int* __restrict__ ci, unsigned int n, unsigned int r,
    unsigned int* sk, unsigned int* si, int tid, int nthreads)
{
    for (unsigned int j = tid; j < n; j += nthreads) { sk[j] = ck[j]; si[j] = ci[j]; }
    __syncthreads();
    for (unsigned int j = tid; j < n; j += nthreads) {
        unsigned int kj = sk[j];
        unsigned int ij = si[j];
        unsigned int rank = 0;
        for (unsigned int i = 0; i < n; ++i) {
            unsigned int ki = sk[i];
            rank += (ki > kj) || (ki == kj && si[i] < ij);
        }
        if (rank < r) {
            unsigned int p = ij % NPIX;
            float* op = o + 3u * p;
            op[0] = 0.0f; op[1] = 0.0f; op[2] = 0.0f;
        }
    }
}

// ==================== fused cooperative single-dispatch kernel ====================
__global__ __launch_bounds__(BLOCK, 8) void fused_all(
    const float* __restrict__ data, const float* __restrict__ grad,
    float* __restrict__ out, unsigned int* __restrict__ hist2,
    unsigned int* __restrict__ candcnt,
    unsigned int* __restrict__ candkey, unsigned int* __restrict__ candidx)
{
    const int smp  = blockIdx.x / SPLIT;
    const int half = blockIdx.x % SPLIT;
    const int tid  = threadIdx.x;

    __shared__ unsigned int lh[NBINS];
    __shared__ unsigned int maskw[NMWH];
    __shared__ unsigned int wtot[NWAVE];
    __shared__ int sB1;
    __shared__ unsigned int sR;
    __shared__ unsigned int sk[MAXCAND];
    __shared__ unsigned int si[MAXCAND];

    for (int i = tid; i < NBINS; i += BLOCK) lh[i] = 0u;
    if (tid == 0 && half == 0) candcnt[smp] = 0u;
    __syncthreads();

    const f4* g4 = (const f4*)(grad + (size_t)smp * NELEM);

    // P1: partial histogram of own half
    hist_accum(g4 + (size_t)half * HGVEC, lh, tid);
    __syncthreads();

    // write own partial hist (plain coalesced stores, no atomics/memset)
    {
        uint4* dst = (uint4*)(hist2 + ((size_t)smp * SPLIT + half) * NBINS);
        uint4 v;
        v.x = lh[4 * tid]; v.y = lh[4 * tid + 1];
        v.z = lh[4 * tid + 2]; v.w = lh[4 * tid + 3];
        dst[tid] = v;
    }

    cg::this_grid().sync();

    // P2: threshold from own (LDS) + other (global) partial — redundant per block
    {
        const unsigned int* hoth = hist2 + ((size_t)smp * SPLIT + (half ^ 1)) * NBINS;
        uint4 ho = ((const uint4*)hoth)[tid];
        threshold_scan(lh[4 * tid] + ho.x, lh[4 * tid + 1] + ho.y,
                       lh[4 * tid + 2] + ho.z, lh[4 * tid + 3] + ho.w,
                       wtot, &sB1, &sR, tid);
    }

    // P3: classify + coalesced masked copy of own half
    const f4* d4 = (const f4*)(data + (size_t)smp * NELEM);
    f4*       o4 = (f4*)(out + (size_t)smp * NELEM);
    classify_copy(g4, d4, o4, half, sB1, maskw,
                  candcnt + smp,
                  candkey + (size_t)smp * MAXCAND,
                  candidx + (size_t)smp * MAXCAND, tid);

    cg::this_grid().sync();

    // P4: candidate ranking fixup (one block per sample)
    if (half == 0) {
        unsigned int n = candcnt[smp];
        if (n > MAXCAND) n = MAXCAND;
        rank_fix(out + (size_t)smp * NELEM,
                 candkey + (size_t)smp * MAXCAND,
                 candidx + (size_t)smp * MAXCAND,
                 n, sR, sk, si, tid, BLOCK);
    }
}

// ==================== 4-kernel fallback pipeline ====================
__global__ __launch_bounds__(BLOCK, 8) void k1_hist(
    const float* __restrict__ grad, unsigned int* __restrict__ hist2)
{
    const int smp  = blockIdx.x / SPLIT;
    const int half = blockIdx.x % SPLIT;
    const int tid  = threadIdx.x;

    __shared__ unsigned int lh[NBINS];
    for (int i = tid; i < NBINS; i += BLOCK) lh[i] = 0u;
    __syncthreads();

    const f4* g4 = (const f4*)(grad + (size_t)smp * NELEM) + (size_t)half * HGVEC;
    hist_accum(g4, lh, tid);
    __syncthreads();

    uint4* dst = (uint4*)(hist2 + ((size_t)smp * SPLIT + half) * NBINS);
    uint4 v;
    v.x = lh[4 * tid]; v.y = lh[4 * tid + 1];
    v.z = lh[4 * tid + 2]; v.w = lh[4 * tid + 3];
    dst[tid] = v;
}

__global__ __launch_bounds__(BLOCK) void k2_thresh(
    const unsigned int* __restrict__ hist2,
    int* __restrict__ B1a, unsigned int* __restrict__ Ra,
    unsigned int* __restrict__ candcnt)
{
    const int smp = blockIdx.x;
    const int tid = threadIdx.x;

    __shared__ unsigned int wtot[NWAVE];
    __shared__ int sB1;
    __shared__ unsigned int sR;

    uint4 h0 = ((const uint4*)(hist2 + ((size_t)smp * SPLIT)     * NBINS))[tid];
    uint4 h1 = ((const uint4*)(hist2 + ((size_t)smp * SPLIT + 1) * NBINS))[tid];
    threshold_scan(h0.x + h1.x, h0.y + h1.y, h0.z + h1.z, h0.w + h1.w,
                   wtot, &sB1, &sR, tid);

    if (tid == 0) {
        B1a[smp] = sB1;
        Ra[smp]  = sR;
        candcnt[smp] = 0u;
    }
}

__global__ __launch_bounds__(BLOCK, 8) void k3_out(
    const float* __restrict__ data, const float* __restrict__ grad,
    float* __restrict__ out, const int* __restrict__ B1a,
    unsigned int* __restrict__ candcnt,
    unsigned int* __restrict__ candkey, unsigned int* __restrict__ candidx)
{
    const int smp  = blockIdx.x / SPLIT;
    const int half = blockIdx.x % SPLIT;
    const int tid  = threadIdx.x;

    __shared__ unsigned int maskw[NMWH];

    const f4* g4 = (const f4*)(grad + (size_t)smp * NELEM);
    const f4* d4 = (const f4*)(data + (size_t)smp * NELEM);
    f4*       o4 = (f4*)(out + (size_t)smp * NELEM);

    classify_copy(g4, d4, o4, half, B1a[smp], maskw,
                  candcnt + smp,
                  candkey + (size_t)smp * MAXCAND,
                  candidx + (size_t)smp * MAXCAND, tid);
}

__global__ __launch_bounds__(BLOCK) void k4_fix(
    float* __restrict__ out,
    const unsigned int* __restrict__ candcnt,
    const unsigned int* __restrict__ candkey,
    const unsigned int* __restrict__ candidx,
    const unsigned int* __restrict__ Ra)
{
    const int smp = blockIdx.x;
    const int tid = threadIdx.x;

    __shared__ unsigned int sk[MAXCAND];
    __shared__ unsigned int si[MAXCAND];

    unsigned int n = candcnt[smp];
    if (n > MAXCAND) n = MAXCAND;
    rank_fix(out + (size_t)smp * NELEM,
             candkey + (size_t)smp * MAXCAND,
             candidx + (size_t)smp * MAXCAND,
             n, Ra[smp], sk, si, tid, BLOCK);
}

// ============== verified single-kernel fallback (tiny workspace) ==============
__global__ __launch_bounds__(BLOCK) void masked_model_kernel(
    const float* __restrict__ data,
    const float* __restrict__ grad,
    float* __restrict__ out)
{
    const int b    = blockIdx.x;
    const int tid  = threadIdx.x;
    const int lane = tid & 63;
    const int wid  = tid >> 6;

    const float* g = grad + (size_t)b * NELEM;
    const float* d = data + (size_t)b * NELEM;
    float*       o = out  + (size_t)b * NELEM;

    __shared__ unsigned int hist[NBINS];
    __shared__ unsigned int mask[NPIX / 32];
    __shared__ unsigned int candkey[MAXCAND];
    __shared__ unsigned int candidx[MAXCAND];
    __shared__ unsigned int wtot[NWAVE];
    __shared__ unsigned int candcnt;
    __shared__ int sB1;
    __shared__ unsigned int sR;

    for (int i = tid; i < NBINS; i += BLOCK) hist[i] = 0u;
    for (int i = tid; i < NPIX / 32; i += BLOCK) mask[i] = 0u;
    if (tid == 0) candcnt = 0u;
    __syncthreads();

    const f4* g4 = (const f4*)g;
    for (int i = tid; i < GVEC; i += BLOCK) {
        f4 v = g4[i];
        #pragma unroll
        for (int c = 0; c < 4; ++c) atomicAdd(&hist[binof(v[c])], 1u);
    }
    __syncthreads();

    {
        unsigned int s = hist[4 * tid] + hist[4 * tid + 1]
                       + hist[4 * tid + 2] + hist[4 * tid + 3];
        unsigned int v = s;
        #pragma unroll
        for (int off = 1; off < 64; off <<= 1) {
            unsigned int u = __shfl_down(v, off);
            if (lane + off < 64) v += u;
        }
        if (lane == 0) wtot[wid] = v;
        __syncthreads();
        unsigned int woff = 0;
        for (int w = wid + 1; w < NWAVE; ++w) woff += wtot[w];
        unsigned int a  = v + woff;
        unsigned int nx = a - s;
        if (a >= KSEL && nx < KSEL) {
            unsigned int cum = nx;
            for (int i = 3; i >= 0; --i) {
                unsigned int h = hist[4 * tid + i];
                cum += h;
                if (cum >= KSEL) { sB1 = 4 * tid + i; sR = KSEL - (cum - h); break; }
            }
        }
    }
    __syncthreads();

    {
        const int B1 = sB1;
        for (int i = tid; i < GVEC; i += BLOCK) {
            f4 v = g4[i];
            #pragma unroll
            for (int c = 0; c < 4; ++c) {
                int bin = binof(v[c]);
                int idx = 4 * i + c;
                if (bin > B1) {
                    int p = idx % NPIX;
                    atomicOr(&mask[p >> 5], 1u << (p & 31));
                } else if (bin == B1) {
                    unsigned int c2 = atomicAdd(&candcnt, 1u);
                    if (c2 < MAXCAND) {
                        candkey[c2] = __float_as_uint(v[c]);
                        candidx[c2] = (unsigned int)idx;
                    }
                }
            }
        }
    }
    __syncthreads();

    {
        unsigned int n = candcnt < MAXCAND ? candcnt : MAXCAND;
        unsigned int r = sR;
        for (unsigned int j = tid; j < n; j += BLOCK) {
            unsigned int kj = candkey[j];
            unsigned int ij = candidx[j];
            unsigned int rank = 0;
            for (unsigned int i = 0; i < n; ++i) {
                unsigned int ki = candkey[i];
                rank += (ki > kj) || (ki == kj && candidx[i] < ij);
            }
            if (rank < r) {
                int p = (int)(ij % NPIX);
                atomicOr(&mask[p >> 5], 1u << (p & 31));
            }
        }
    }
    __syncthreads();

    {
        const f4* d4 = (const f4*)d;
        f4*       o4 = (f4*)o;
        for (int i = tid; i < GVEC; i += BLOCK) {
            f4 v = d4[i];
            int e = 4 * i;
            int p0 = e / 3, p1 = (e + 1) / 3, p2 = (e + 2) / 3, p3 = (e + 3) / 3;
            if ((mask[p0 >> 5] >> (p0 & 31)) & 1u) v.x = 0.0f;
            if ((mask[p1 >> 5] >> (p1 & 31)) & 1u) v.y = 0.0f;
            if ((mask[p2 >> 5] >> (p2 & 31)) & 1u) v.z = 0.0f;
            if ((mask[p3 >> 5] >> (p3 & 31)) & 1u) v.w = 0.0f;
            o4[i] = v;
        }
    }
}

extern "C" void kernel_launch(void* const* d_in, const int* in_sizes, int n_in,
                              void* d_out, int out_size, void* d_ws, size_t ws_size,
                              hipStream_t stream) {
    const float* data = (const float*)d_in[0];   // [256, 224, 224, 3] fp32
    const float* grad = (const float*)d_in[1];   // [256, 150528] fp32
    float* out = (float*)d_out;                  // [256, 224, 224, 3] fp32

    const int B = in_sizes[0] / NELEM;           // 256

    // ws layout (u32): hist2[B][2][4096] | candcnt[B] | B1[B] | R[B]
    //                | candkey[B][MAXCAND] | candidx[B][MAXCAND]
    const size_t histB  = (size_t)B * SPLIT * NBINS * 4;
    const size_t cntB   = (size_t)B * 4;
    const size_t candB  = (size_t)B * MAXCAND * 4;
    const size_t needed = histB + 3 * cntB + 2 * candB;

    if (ws_size < needed) {
        masked_model_kernel<<<B, BLOCK, 0, stream>>>(data, grad, out);
        return;
    }

    char* ws = (char*)d_ws;
    unsigned int* hist2   = (unsigned int*)(ws);
    unsigned int* candcnt = (unsigned int*)(ws + histB);
    int*          B1a     = (int*)         (ws + histB + cntB);
    unsigned int* Ra      = (unsigned int*)(ws + histB + 2 * cntB);
    unsigned int* candkey = (unsigned int*)(ws + histB + 3 * cntB);
    unsigned int* candidx = (unsigned int*)(ws + histB + 3 * cntB + candB);

    // try single-dispatch cooperative kernel (2 blocks/CU co-resident)
    void* args[] = { (void*)&data, (void*)&grad, (void*)&out, (void*)&hist2,
                     (void*)&candcnt, (void*)&candkey, (void*)&candidx };
    hipError_t e = hipLaunchCooperativeKernel((const void*)fused_all,
                                              dim3(B * SPLIT), dim3(BLOCK),
                                              args, 0, stream);
    if (e != hipSuccess) {
        (void)hipGetLastError();   // clear sticky error; use pipeline instead
        k1_hist  <<<B * SPLIT, BLOCK, 0, stream>>>(grad, hist2);
        k2_thresh<<<B,         BLOCK, 0, stream>>>(hist2, B1a, Ra, candcnt);
        k3_out   <<<B * SPLIT, BLOCK, 0, stream>>>(data, grad, out, B1a,
                                                   candcnt, candkey, candidx);
        k4_fix   <<<B,         BLOCK, 0, stream>>>(out, candcnt, candkey,
                                                   candidx, Ra);
    }
}